// Round 13
// baseline (225.791 us; speedup 1.0000x reference)
//
#include <hip/hip_runtime.h>
#include <hip/hip_bf16.h>
#include <stdint.h>

namespace {

constexpr int B = 8, T = 200, U = 50, D = 512, INNER = 640, VOCAB = 1024;
constexpr int M_TOTAL = B * T * U;          // 80000
constexpr int ROWS_E = B * T;               // 1600
constexpr int ROWS_D = B * U;               // 400
constexpr int ROWS_ED = ROWS_E + ROWS_D;    // 2000

typedef __bf16 bf16x8 __attribute__((ext_vector_type(8)));
typedef float  f32x4  __attribute__((ext_vector_type(4)));
typedef int    i32x4  __attribute__((ext_vector_type(4)));
typedef unsigned short u16;
typedef unsigned int   u32;

constexpr size_t ED_BYTES  = (size_t)ROWS_ED * INNER * 4;      // 5,120,000
constexpr size_t W2B_BYTES = (size_t)VOCAB * INNER * 2;        // 1,310,720
constexpr size_t H_BYTES   = (size_t)M_TOTAL * INNER * 2;      // 102,400,000
constexpr size_t WS_NEED   = ED_BYTES + W2B_BYTES + H_BYTES;   // 108,830,720

__device__ __forceinline__ u16 f2bf(float f) {
  uint32_t u = __float_as_uint(f);
  uint32_t rounding = 0x7FFFu + ((u >> 16) & 1u);   // RNE
  return (u16)((u + rounding) >> 16);
}

__device__ __forceinline__ float fast_tanh(float x) {
  float e = __expf(2.0f * x);
  float r = __builtin_amdgcn_rcpf(e + 1.0f);
  return 1.0f - 2.0f * r;
}

#define GLD16(gp, lp) __builtin_amdgcn_global_load_lds( \
    (const __attribute__((address_space(1))) u32*)(gp), \
    (__attribute__((address_space(3))) u32*)(lp), 16, 0, 0)

// ---------------------------------------------------------------------------
// k_prep: merged GEMM1 (ED) + W2 fragment pack (proven R5-R12).
// ---------------------------------------------------------------------------
__global__ __launch_bounds__(320) void k_prep(const float* __restrict__ enc,
                                              const float* __restrict__ dec,
                                              const float* __restrict__ W1,
                                              const float* __restrict__ b1,
                                              const float* __restrict__ W2,
                                              float* __restrict__ ED,
                                              u16* __restrict__ W2B) {
  if (blockIdx.x >= 500) {
    const int idx = (blockIdx.x - 500) * 320 + threadIdx.x;   // < 81920 exact
    const int lane = idx & 63;
    const int f = idx >> 6;
    const int ks = f >> 6;
    const int nf = f & 63;
    const int n = nf * 16 + (lane & 15);
    const int k = ks * 32 + (lane >> 4) * 8;
    u16 v[8];
#pragma unroll
    for (int j = 0; j < 8; ++j)
      v[j] = f2bf(W2[(size_t)(k + j) * VOCAB + n]);
    uint64_t lo = (uint64_t)v[0] | ((uint64_t)v[1] << 16) |
                  ((uint64_t)v[2] << 32) | ((uint64_t)v[3] << 48);
    uint64_t hi = (uint64_t)v[4] | ((uint64_t)v[5] << 16) |
                  ((uint64_t)v[6] << 32) | ((uint64_t)v[7] << 48);
    uint64_t* dst = reinterpret_cast<uint64_t*>(W2B + (size_t)idx * 8);
    dst[0] = lo;
    dst[1] = hi;
    return;
  }

  __shared__ float rows[4 * D];   // 8 KiB
  const int r0 = blockIdx.x * 4;
  const bool is_enc = (r0 < ROWS_E);
  const float* src = is_enc ? (enc + (size_t)r0 * D)
                            : (dec + (size_t)(r0 - ROWS_E) * D);
  for (int i = threadIdx.x; i < 4 * D; i += 320) rows[i] = src[i];
  __syncthreads();

  const int c0 = threadIdx.x, c1 = threadIdx.x + 320;
  float acc[4][2];
  const float bias0 = is_enc ? b1[c0] : 0.f;
  const float bias1 = is_enc ? b1[c1] : 0.f;
#pragma unroll
  for (int r = 0; r < 4; ++r) { acc[r][0] = bias0; acc[r][1] = bias1; }

  for (int d = 0; d < D; d += 8) {
    f32x4 rv[4][2];
#pragma unroll
    for (int r = 0; r < 4; ++r) {
      rv[r][0] = *reinterpret_cast<const f32x4*>(&rows[r * D + d]);
      rv[r][1] = *reinterpret_cast<const f32x4*>(&rows[r * D + d + 4]);
    }
#pragma unroll
    for (int dd = 0; dd < 8; ++dd) {
      const float w0 = W1[(size_t)(d + dd) * INNER + c0];
      const float w1 = W1[(size_t)(d + dd) * INNER + c1];
#pragma unroll
      for (int r = 0; r < 4; ++r) {
        const float x = rv[r][dd >> 2][dd & 3];
        acc[r][0] = fmaf(x, w0, acc[r][0]);
        acc[r][1] = fmaf(x, w1, acc[r][1]);
      }
    }
  }
#pragma unroll
  for (int r = 0; r < 4; ++r) {
    ED[(size_t)(r0 + r) * INNER + c0] = acc[r][0];
    ED[(size_t)(r0 + r) * INNER + c1] = acc[r][1];
  }
}

// ---------------------------------------------------------------------------
// k_h: H = tanh(E1 + D1) in MFMA A-fragment order (verified end-to-end R9).
// REGULAR stores (not NT): H stays L2/L3-resident for k_main.
// Frag (mg, ksg) at byte (mg*20+ksg)*1024; lane l holds 8 bf16
//   {m = mg*16 + (l&15), k = ksg*32 + (l>>4)*8 + j}.
// ---------------------------------------------------------------------------
__global__ __launch_bounds__(256) void k_h(const float* __restrict__ ED,
                                           u16* __restrict__ H) {
  const int lane = threadIdx.x & 63;
  const int mg = blockIdx.x * 4 + (threadIdx.x >> 6);   // 0..4999
  const int m = mg * 16 + (lane & 15);
  const int b = m / (T * U);
  const int rem = m - b * (T * U);
  const int t = rem / U;
  const int u = rem - t * U;
  const float* E  = ED + (size_t)(b * T + t) * INNER + (lane >> 4) * 8;
  const float* Dv = ED + (size_t)(ROWS_E + b * U + u) * INNER + (lane >> 4) * 8;
  u16* W = H + (size_t)mg * 20 * 512 + lane * 8;

#pragma unroll 4
  for (int ksg = 0; ksg < 20; ++ksg) {
    const f32x4 e0 = *reinterpret_cast<const f32x4*>(E + ksg * 32);
    const f32x4 e1 = *reinterpret_cast<const f32x4*>(E + ksg * 32 + 4);
    const f32x4 d0 = *reinterpret_cast<const f32x4*>(Dv + ksg * 32);
    const f32x4 d1 = *reinterpret_cast<const f32x4*>(Dv + ksg * 32 + 4);
    i32x4 pk;
    pk.x = (int)((u32)f2bf(fast_tanh(e0[0] + d0[0])) |
                 ((u32)f2bf(fast_tanh(e0[1] + d0[1])) << 16));
    pk.y = (int)((u32)f2bf(fast_tanh(e0[2] + d0[2])) |
                 ((u32)f2bf(fast_tanh(e0[3] + d0[3])) << 16));
    pk.z = (int)((u32)f2bf(fast_tanh(e1[0] + d1[0])) |
                 ((u32)f2bf(fast_tanh(e1[1] + d1[1])) << 16));
    pk.w = (int)((u32)f2bf(fast_tanh(e1[2] + d1[2])) |
                 ((u32)f2bf(fast_tanh(e1[3] + d1[3])) << 16));
    *reinterpret_cast<i32x4*>(W + (size_t)ksg * 512) = pk;
  }
}

// ---------------------------------------------------------------------------
// k_main: pure GEMM out = H @ W2 + b2, counted-vmcnt pipeline (T3/T4-lite).
// Tile 128x256, BK=64, nt=10. 512 thr = 8 waves 2Mx4N, wave 64x64, acc[4][4].
// LDS: 2 bufs x (A 16KB + B 32KB) = 96 KB. global_load_lds staging;
// schedule per tile t (fully unrolled, literal vmcnt):
//   consume(t) -> lgkmcnt(0)+s_barrier  [reads done; rule-18 safe]
//   stage(t+2 -> buf[t&1])              [buffer certified free]
//   vmcnt(6)+s_barrier                  [t+1 ready; t+2's 6 stay IN FLIGHT]
// Never vmcnt(0) mid-loop. Regular out stores (L2 absorbs; async writeback).
// ---------------------------------------------------------------------------
__global__ __launch_bounds__(512, 2) void k_main(const u16* __restrict__ H,
                                                 const u16* __restrict__ W2B,
                                                 const float* __restrict__ b2,
                                                 float* __restrict__ out) {
  __shared__ char smem[2][49152];   // per buf: A frags @0 (16KB), B frags @16384 (32KB)

  const int tid  = threadIdx.x;
  const int lane = tid & 63;
  const int wid  = tid >> 6;        // 0..7
  const int wr = wid >> 2, wc = wid & 3;
  const int llo = lane & 15, lhi = lane >> 4;
  const int lane16 = lane * 16;

  const int m0  = blockIdx.x * 128;
  const int n0  = blockIdx.y * 256;
  const int mg0 = blockIdx.x * 8;
  const int nf0 = blockIdx.y * 16;

  const char* Hb = reinterpret_cast<const char*>(H);
  const char* Wb = reinterpret_cast<const char*>(W2B);

  // stage tile t (BK=64 = global ks 2t,2t+1) into buffer s; 6 issues/wave
  auto STAGE = [&](int t, int s) __attribute__((always_inline)) {
    char* base = smem[s];
#pragma unroll
    for (int j = 0; j < 2; ++j) {   // A frags: (mgl=wid, ksl=j)
      const char* g = Hb + (((size_t)(mg0 + wid) * 20 + 2 * t + j) << 10) + lane16;
      GLD16(g, base + ((wid * 2 + j) << 10));
    }
#pragma unroll
    for (int jj = 0; jj < 4; ++jj) {   // B frags f = wid*4+jj in [0,32)
      const int f = wid * 4 + jj;
      const char* g = Wb + (((size_t)(2 * t + (f >> 4)) * 64 + nf0 + (f & 15)) << 10) + lane16;
      GLD16(g, base + 16384 + (f << 10));
    }
  };

  f32x4 acc[4][4];
#pragma unroll
  for (int mi = 0; mi < 4; ++mi)
#pragma unroll
    for (int ni = 0; ni < 4; ++ni) acc[mi][ni] = (f32x4){0.f, 0.f, 0.f, 0.f};

  // ---- prologue: 2-deep ----
  STAGE(0, 0);
  STAGE(1, 1);
  asm volatile("s_waitcnt vmcnt(6)" ::: "memory");   // tile0 done, tile1 in flight
  asm volatile("s_barrier" ::: "memory");

#pragma unroll
  for (int t = 0; t < 10; ++t) {
    const char* base = smem[t & 1];
#pragma unroll
    for (int ksl = 0; ksl < 2; ++ksl) {
      bf16x8 a[4], bfr[4];
#pragma unroll
      for (int mi = 0; mi < 4; ++mi)
        a[mi] = *reinterpret_cast<const bf16x8*>(
            base + (((wr * 4 + mi) * 2 + ksl) << 10) + lane16);
#pragma unroll
      for (int ni = 0; ni < 4; ++ni)
        bfr[ni] = *reinterpret_cast<const bf16x8*>(
            base + 16384 + ((ksl * 16 + wc * 4 + ni) << 10) + lane16);
      __builtin_amdgcn_s_setprio(1);
#pragma unroll
      for (int mi = 0; mi < 4; ++mi)
#pragma unroll
        for (int ni = 0; ni < 4; ++ni)
          acc[mi][ni] = __builtin_amdgcn_mfma_f32_16x16x32_bf16(a[mi], bfr[ni], acc[mi][ni], 0, 0, 0);
      __builtin_amdgcn_s_setprio(0);
    }
    // consumption-done certificate (ds_reads complete before anyone restages)
    asm volatile("s_waitcnt lgkmcnt(0)" ::: "memory");
    asm volatile("s_barrier" ::: "memory");
    if (t + 2 < 10) STAGE(t + 2, t & 1);
    if (t + 1 < 10) {
      if (t + 2 < 10) {
        asm volatile("s_waitcnt vmcnt(6)" ::: "memory");   // t+1 done; t+2 in flight
      } else {
        asm volatile("s_waitcnt vmcnt(0)" ::: "memory");   // t=8: only t+1 out
      }
      asm volatile("s_barrier" ::: "memory");
    }
  }

  // ---- epilogue (regular stores) ----
  float b2v[4];
#pragma unroll
  for (int ni = 0; ni < 4; ++ni) b2v[ni] = b2[n0 + wc * 64 + ni * 16 + llo];

#pragma unroll
  for (int mi = 0; mi < 4; ++mi) {
#pragma unroll
    for (int q = 0; q < 4; ++q) {
      const int row = m0 + wr * 64 + mi * 16 + lhi * 4 + q;
      float* orow = out + (size_t)row * VOCAB + n0 + wc * 64 + llo;
#pragma unroll
      for (int ni = 0; ni < 4; ++ni)
        orow[ni * 16] = acc[mi][ni][q] + b2v[ni];
    }
  }
}

// ---------------------------------------------------------------------------
// FALLBACK (ws too small for H): R7's fused path — proven 178.6 µs.
// ---------------------------------------------------------------------------
__global__ __launch_bounds__(512, 4) void k_main_fused(const float* __restrict__ ED,
                                                       const u16* __restrict__ W2B,
                                                       const float* __restrict__ b2,
                                                       float* __restrict__ out) {
  constexpr int CK = 128, NCHUNK = 5, CHUNK_B = 16 * 1024;
  __shared__ u16 At[2 * CHUNK_B / 2];
  char* At_b = reinterpret_cast<char*>(At);

  const int tid = threadIdx.x;
  const int m0 = blockIdx.x * 64;
  const int n0 = blockIdx.y * 512;

  const int row0 = tid >> 4;
  const int g    = tid & 15;
  int eoff[2], doff[2], wbyte[2];
#pragma unroll
  for (int i = 0; i < 2; ++i) {
    const int row = row0 + i * 32;
    const int m = m0 + row;
    const int b = m / (T * U);
    const int rem = m - b * (T * U);
    const int t = rem / U;
    const int u = rem - t * U;
    eoff[i] = (b * T + t) * INNER;
    doff[i] = (ROWS_E + b * U + u) * INNER;
    wbyte[i] = (((row >> 4) * 4 + (g >> 2)) << 10) + ((g & 3) * 16 + (row & 15)) * 16;
  }

  auto tanh_chunk = [&](int c, int bufsel) __attribute__((always_inline)) {
    const int kb = c * CK + g * 8;
#pragma unroll
    for (int i = 0; i < 2; ++i) {
      const float* E = ED + eoff[i] + kb;
      const float* Dp = ED + doff[i] + kb;
      const f32x4 e0 = *reinterpret_cast<const f32x4*>(E);
      const f32x4 e1 = *reinterpret_cast<const f32x4*>(E + 4);
      const f32x4 d0 = *reinterpret_cast<const f32x4*>(Dp);
      const f32x4 d1 = *reinterpret_cast<const f32x4*>(Dp + 4);
      const u32 p0 = (u32)f2bf(fast_tanh(e0[0] + d0[0])) |
                     ((u32)f2bf(fast_tanh(e0[1] + d0[1])) << 16);
      const u32 p1 = (u32)f2bf(fast_tanh(e0[2] + d0[2])) |
                     ((u32)f2bf(fast_tanh(e0[3] + d0[3])) << 16);
      const u32 p2 = (u32)f2bf(fast_tanh(e1[0] + d1[0])) |
                     ((u32)f2bf(fast_tanh(e1[1] + d1[1])) << 16);
      const u32 p3 = (u32)f2bf(fast_tanh(e1[2] + d1[2])) |
                     ((u32)f2bf(fast_tanh(e1[3] + d1[3])) << 16);
      int4 pk; pk.x = (int)p0; pk.y = (int)p1; pk.z = (int)p2; pk.w = (int)p3;
      *reinterpret_cast<int4*>(At_b + bufsel * CHUNK_B + wbyte[i]) = pk;
    }
  };

  const int lane = tid & 63;
  const int w    = tid >> 6;
  const int llo  = lane & 15;
  const int lhi  = lane >> 4;
  const u16* Bp = W2B + ((size_t)((n0 >> 4) + w * 4) << 9) + lane * 8;

  f32x4 acc[4][4];
#pragma unroll
  for (int mi = 0; mi < 4; ++mi)
#pragma unroll
    for (int ni = 0; ni < 4; ++ni) acc[mi][ni] = (f32x4){0.f, 0.f, 0.f, 0.f};

  tanh_chunk(0, 0);
  __syncthreads();

  for (int c = 0; c < NCHUNK; ++c) {
    const int ab = (c & 1) * CHUNK_B;
    if (c < NCHUNK - 1) tanh_chunk(c + 1, (c + 1) & 1);
#pragma unroll
    for (int ks = 0; ks < 4; ++ks) {
      bf16x8 bfr[4], a[4];
#pragma unroll
      for (int ni = 0; ni < 4; ++ni)
        bfr[ni] = *reinterpret_cast<const bf16x8*>(
            Bp + ((size_t)((c * 4 + ks) * 64 + ni) << 9));
#pragma unroll
      for (int mi = 0; mi < 4; ++mi)
        a[mi] = *reinterpret_cast<const bf16x8*>(
            At_b + ab + ((mi * 4 + ks) << 10) + lane * 16);
#pragma unroll
      for (int mi = 0; mi < 4; ++mi)
#pragma unroll
        for (int ni = 0; ni < 4; ++ni)
          acc[mi][ni] = __builtin_amdgcn_mfma_f32_16x16x32_bf16(a[mi], bfr[ni], acc[mi][ni], 0, 0, 0);
    }
    __syncthreads();
  }

  float b2v[4];
#pragma unroll
  for (int ni = 0; ni < 4; ++ni) b2v[ni] = b2[n0 + w * 64 + ni * 16 + llo];
#pragma unroll
  for (int mi = 0; mi < 4; ++mi) {
#pragma unroll
    for (int q = 0; q < 4; ++q) {
      const int row = m0 + mi * 16 + lhi * 4 + q;
      float* orow = out + (size_t)row * VOCAB + n0 + w * 64 + llo;
#pragma unroll
      for (int ni = 0; ni < 4; ++ni)
        orow[ni * 16] = acc[mi][ni][q] + b2v[ni];
    }
  }
}

}  // namespace

extern "C" void kernel_launch(void* const* d_in, const int* in_sizes, int n_in,
                              void* d_out, int out_size, void* d_ws, size_t ws_size,
                              hipStream_t stream) {
  const float* enc = (const float*)d_in[0];
  const float* dec = (const float*)d_in[1];
  const float* W1  = (const float*)d_in[2];
  const float* b1  = (const float*)d_in[3];
  const float* W2  = (const float*)d_in[4];
  const float* b2  = (const float*)d_in[5];
  float* out = (float*)d_out;

  float* ED  = (float*)d_ws;
  u16*   W2B = (u16*)((char*)d_ws + ED_BYTES);
  u16*   H   = (u16*)((char*)d_ws + ED_BYTES + W2B_BYTES);

  hipLaunchKernelGGL(k_prep, dim3(756), dim3(320), 0, stream,
                     enc, dec, W1, b1, W2, ED, W2B);

  if (ws_size >= WS_NEED) {
    hipLaunchKernelGGL(k_h, dim3(1250), dim3(256), 0, stream, ED, H);
    hipLaunchKernelGGL(k_main, dim3(M_TOTAL / 128, VOCAB / 256), dim3(512),
                       0, stream, H, W2B, b2, out);
  } else {
    hipLaunchKernelGGL(k_main_fused, dim3(M_TOTAL / 64, VOCAB / 512), dim3(512),
                       0, stream, ED, W2B, b2, out);
  }
}